// Round 4
// baseline (56.999 us; speedup 1.0000x reference)
//
#include <hip/hip_runtime.h>

typedef float f4 __attribute__((ext_vector_type(4)));

constexpr int D  = 128;
constexpr int B  = 1024;
constexpr int S1 = 25;    // inner fanout (hop2 -> hop1)
constexpr int S2 = 10;    // outer fanout (hop1 -> hop0)

// ---------------------------------------------------------------------------
// Fully-fused SAGE kernel: ONE block per output row b (1024 blocks, 256 thr).
//   Gathers h0[b], h1[b*10..+10), h2[b*250..+250) once; computes the 10 nh1
//   rows + nh0 entirely on-chip; writes only out[b] (128 floats).
//   Eliminates: nh1/nh0 global round-trip (11.4 MB), h1 double-gather (5 MB),
//   the second kernel launch, and the layer-1 tail.
//   Staging via global_load_lds (R3-proven to saturate the random-row service
//   rate): 2 rounds x 125 neighbor rows (nbuf 126 rows, single-buffered;
//   cross-block phase offset at 2 blocks/CU hides the reduce/matmul gaps).
//   LDS: 126*512 + 2*12*512 + 4*512 = 77.5 KB -> 2 blocks/CU, 8 waves/CU.
// ---------------------------------------------------------------------------

#define GLD16(src, dst) __builtin_amdgcn_global_load_lds(                      \
    (const __attribute__((address_space(1))) void*)(src),                      \
    (__attribute__((address_space(3))) void*)(dst), 16, 0, 0)

// mean over N consecutive rows of src (row stride D) -> dst[0..127]
template <int N>
__device__ __forceinline__ void mean_rows(const float* src, float* dst, int lane)
{
    const int c = lane & 31;
    const int h = lane >> 5;
    constexpr int H = (N + 1) / 2;
    f4 acc = {0.f, 0.f, 0.f, 0.f};
    #pragma unroll
    for (int k = 0; k < H; ++k) {
        const int s = h * H + k;
        if (s < N)
            acc += *(const f4*)(src + (long)s * D + c * 4);
    }
    acc.x += __shfl_xor(acc.x, 32);
    acc.y += __shfl_xor(acc.y, 32);
    acc.z += __shfl_xor(acc.z, 32);
    acc.w += __shfl_xor(acc.w, 32);
    if (h == 0)
        *(f4*)(dst + c * 4) = acc * (1.f / N);
}

// prefetch the 16 (or 15) pair-indices this wave stages in one round
__device__ __forceinline__ void prefetch_idx(const int* __restrict__ nidx,
                                             int w, int half, int* gi)
{
    #pragma unroll
    for (int i = 0; i < 16; ++i) {
        const int p2 = w + i * 4;
        if (p2 < 63) {
            int jj = 2 * p2 + half;
            if (jj > 124) jj = 124;        // pair 62 duplicates row 124
            gi[i] = nidx[jj];
        }
    }
}

// issue the wave's global_load_lds pair stores for one 125-row round
__device__ __forceinline__ void issue_pairs(const float* __restrict__ feat,
                                            const int* gi, int w, int lane,
                                            float* nbuf)
{
    #pragma unroll
    for (int i = 0; i < 16; ++i) {
        const int p2 = w + i * 4;
        if (p2 < 63)
            GLD16(feat + (size_t)gi[i] * D + (lane & 31) * 4,
                  nbuf + (long)p2 * 2 * D);
    }
}

__global__ __launch_bounds__(256, 2) void sage_fused_kernel(
    const float* __restrict__ feat,
    const int* __restrict__ s0, const int* __restrict__ s1,
    const int* __restrict__ s2,
    const float* __restrict__ Ws0, const float* __restrict__ Wn0,
    const float* __restrict__ Ws1, const float* __restrict__ Wn1,
    float* __restrict__ out)
{
    __shared__ float nbuf[126 * D];    // neighbor staging (125 rows + dup)
    __shared__ float hbuf[12 * D];     // h1 rows 0-9, h0 row 10, zero row 11
    __shared__ float mbuf[12 * D];     // means 0-9, mh1 row 10, zero row 11
    __shared__ float xpart[2 * D];     // relu-row partial sums (per rh half)
    __shared__ float xnh0[D];          // nh0 row
    __shared__ float x2[2 * D];        // stage-2 k-half partials

    const int b    = blockIdx.x;
    const int t    = threadIdx.x;
    const int w    = t >> 6;
    const int lane = t & 63;
    const int half = lane >> 5;

    const int* __restrict__ nidx0 = s2 + (size_t)b * 250;
    const int* __restrict__ nidx1 = nidx0 + 125;

    // ---- phase S0: prefetch idx, issue round-0 neighbors + h1 + h0 --------
    int gi0[16], gi1[16];
    prefetch_idx(nidx0, w, half, gi0);
    const int gih  = s1[b * 10 + 2 * w + half];          // h1 pair w (rows 2w,2w+1)
    int gih4 = 0, gih0 = 0;
    if (w == 0) gih4 = s1[b * 10 + 8 + half];            // h1 pair 4 (rows 8,9)
    if (w == 1) gih0 = s0[b];                            // h0 dup-pair (rows 10,11)

    issue_pairs(feat, gi0, w, lane, nbuf);
    GLD16(feat + (size_t)gih * D + (lane & 31) * 4, hbuf + 2 * w * D);
    if (w == 0) GLD16(feat + (size_t)gih4 * D + (lane & 31) * 4, hbuf + 8 * D);
    if (w == 1) GLD16(feat + (size_t)gih0 * D + (lane & 31) * 4, hbuf + 10 * D);

    prefetch_idx(nidx1, w, half, gi1);   // round-1 idx in flight during reduce
    __syncthreads();                     // drains all staging loads

    // ---- phase RD0: means 0-4 (+ mh1 from h1 rows) -------------------------
    mean_rows<25>(nbuf + (long)w * 25 * D, mbuf + (long)w * D, lane);
    if (w == 0) mean_rows<25>(nbuf + 4L * 25 * D, mbuf + 4L * D, lane);
    if (w == 2) mean_rows<10>(hbuf, mbuf + 10L * D, lane);
    __syncthreads();

    // ---- phase S1: issue round-1 neighbors; zero dummy rows ---------------
    issue_pairs(feat, gi1, w, lane, nbuf);
    if (t < 128) hbuf[11 * D + t] = 0.f;
    else         mbuf[11 * D + (t - 128)] = 0.f;
    __syncthreads();

    // ---- phase RD1: means 5-9 ---------------------------------------------
    mean_rows<25>(nbuf + (long)w * 25 * D, mbuf + (long)(5 + w) * D, lane);
    if (w == 0) mean_rows<25>(nbuf + 4L * 25 * D, mbuf + 9L * D, lane);
    __syncthreads();

    // ---- phase MM1: 12-row batched matmul (rows 0-9 nh1, 10 nh0, 11 dummy)
    const int d  = t & 127;
    const int rh = t >> 7;
    float acc[6] = {0.f, 0.f, 0.f, 0.f, 0.f, 0.f};

    #pragma unroll 4
    for (int k4 = 0; k4 < D / 4; ++k4) {
        const int k = k4 * 4;
        const float ws0 = Ws0[(k + 0) * D + d], ws1 = Ws0[(k + 1) * D + d],
                    ws2 = Ws0[(k + 2) * D + d], ws3 = Ws0[(k + 3) * D + d];
        const float wn0 = Wn0[(k + 0) * D + d], wn1 = Wn0[(k + 1) * D + d],
                    wn2 = Wn0[(k + 2) * D + d], wn3 = Wn0[(k + 3) * D + d];
        #pragma unroll
        for (int r = 0; r < 6; ++r) {
            const int i = rh * 6 + r;
            const f4 hv = *(const f4*)(&hbuf[(long)i * D + k]);
            const f4 mv = *(const f4*)(&mbuf[(long)i * D + k]);
            acc[r] += hv.x * ws0 + hv.y * ws1 + hv.z * ws2 + hv.w * ws3
                    + mv.x * wn0 + mv.y * wn1 + mv.z * wn2 + mv.w * wn3;
        }
    }

    // relu + fold: rh=0 owns nh1 rows 0-5; rh=1 owns nh1 rows 6-9 and nh0 (10)
    float part = 0.f;
    if (rh == 0) {
        #pragma unroll
        for (int r = 0; r < 6; ++r) part += fmaxf(acc[r], 0.f);
    } else {
        #pragma unroll
        for (int r = 0; r < 4; ++r) part += fmaxf(acc[r], 0.f);
        xnh0[d] = fmaxf(acc[4], 0.f);
    }
    xpart[rh * D + d] = part;
    __syncthreads();

    // ---- phase MM2: out[b] = nh0 @ Ws1 + mean(nh1) @ Wn1 ------------------
    float a2 = 0.f;
    #pragma unroll 8
    for (int kk = 0; kk < 64; ++kk) {
        const int k  = rh * 64 + kk;
        const float v0 = xnh0[k];
        const float v1 = (xpart[k] + xpart[D + k]) * (1.f / S2);
        a2 += v0 * Ws1[(long)k * D + d] + v1 * Wn1[(long)k * D + d];
    }
    x2[rh * D + d] = a2;
    __syncthreads();

    if (t < 128)
        out[(size_t)b * D + t] = x2[t] + x2[D + t];
}

extern "C" void kernel_launch(void* const* d_in, const int* in_sizes, int n_in,
                              void* d_out, int out_size, void* d_ws, size_t ws_size,
                              hipStream_t stream)
{
    const float* feat = (const float*)d_in[0];
    const float* Ws0  = (const float*)d_in[1];
    const float* Wn0  = (const float*)d_in[2];
    const float* Ws1  = (const float*)d_in[3];
    const float* Wn1  = (const float*)d_in[4];
    const int*   s0   = (const int*)d_in[5];
    const int*   s1   = (const int*)d_in[6];
    const int*   s2   = (const int*)d_in[7];
    float* out = (float*)d_out;

    sage_fused_kernel<<<B, 256, 0, stream>>>(feat, s0, s1, s2,
                                             Ws0, Wn0, Ws1, Wn1, out);
}